// Round 17
// baseline (78.932 us; speedup 1.0000x reference)
//
#include <hip/hip_runtime.h>
#include <cstdint>
#include <cstddef>

#define N_TOK  16384
#define NEXP   64
#define KDIM   2048
#define CAP    256   // ceil(16384/64 * 1.0) = 256
#define NE_TOT ((size_t)N_TOK * NEXP)

typedef __attribute__((ext_vector_type(8))) short short8;
typedef __attribute__((ext_vector_type(4))) float f32x4;
typedef __attribute__((ext_vector_type(4))) unsigned int uint4x;

__device__ __forceinline__ unsigned short bf16_rtn(float f) {
  unsigned u = __float_as_uint(f);
  u += 0x7FFFu + ((u >> 16) & 1u);
  return (unsigned short)(u >> 16);
}
__device__ __forceinline__ float bf16_f(unsigned short h) {
  return __uint_as_float((unsigned)h << 16);
}
__device__ __forceinline__ f32x4 MF(short8 a, short8 b, f32x4 c) {
  return __builtin_amdgcn_mfma_f32_16x16x32_bf16(a, b, c, 0, 0, 0);
}
// HW packed f32->bf16 RTNE (bit-identical to bf16_rtn; verified R6->R7)
__device__ __forceinline__ unsigned cvt_pk(float a, float b) {
  unsigned r;
  asm("v_cvt_pk_bf16_f32 %0, %1, %2" : "=v"(r) : "v"(a), "v"(b));
  return r;
}
__device__ __forceinline__ float lo16f(unsigned u) {
  return __uint_as_float(u << 16);
}
__device__ __forceinline__ float hi16f(unsigned u) {
  return __uint_as_float(u & 0xFFFF0000u);
}

// ---------------------------------------------------------------------------
// Kernel 0: split W into 3 bf16 digits, packed [k/8][col][8] (unchanged).
// ---------------------------------------------------------------------------
__global__ __launch_bounds__(256) void wdigits(const float* __restrict__ W,
    unsigned short* __restrict__ Wh, unsigned short* __restrict__ Wl,
    unsigned short* __restrict__ Wq) {
  const int e = (int)blockIdx.x * 256 + (int)threadIdx.x;  // 0..131071
  const int col = e >> 11;
  const int k   = e & 2047;
  const float w = W[(size_t)col * KDIM + k];
  const unsigned short h = bf16_rtn(w);
  const float r1 = w - bf16_f(h);
  const unsigned short lo = bf16_rtn(r1);
  const float r2 = r1 - bf16_f(lo);
  const unsigned short q = bf16_rtn(r2);
  const size_t idx = (size_t)(k >> 3) * 512 + (size_t)col * 8 + (k & 7);
  Wh[idx] = h; Wl[idx] = lo; Wq[idx] = q;
}

// ---------------------------------------------------------------------------
// Kernel 1: logits via 6-term split-bf16 MFMA (R16 verbatim — verified
//   74.36us / absmax 0.0009765625; gload_lds wave-private staging).
// ---------------------------------------------------------------------------
__device__ __forceinline__ void cvt8pk(float4 a, float4 b,
                                       short8& h, short8& lo, short8& q) {
  const float f0 = a.x, f1 = a.y, f2 = a.z, f3 = a.w;
  const float f4 = b.x, f5 = b.y, f6 = b.z, f7 = b.w;
  const unsigned h0 = cvt_pk(f0, f1), h1 = cvt_pk(f2, f3);
  const unsigned h2 = cvt_pk(f4, f5), h3 = cvt_pk(f6, f7);
  const float r0 = f0 - lo16f(h0), r1 = f1 - hi16f(h0);
  const float r2 = f2 - lo16f(h1), r3 = f3 - hi16f(h1);
  const float r4 = f4 - lo16f(h2), r5 = f5 - hi16f(h2);
  const float r6 = f6 - lo16f(h3), r7 = f7 - hi16f(h3);
  const unsigned l0 = cvt_pk(r0, r1), l1 = cvt_pk(r2, r3);
  const unsigned l2 = cvt_pk(r4, r5), l3 = cvt_pk(r6, r7);
  const float s0 = r0 - lo16f(l0), s1 = r1 - hi16f(l0);
  const float s2 = r2 - lo16f(l1), s3 = r3 - hi16f(l1);
  const float s4 = r4 - lo16f(l2), s5 = r5 - hi16f(l2);
  const float s6 = r6 - lo16f(l3), s7 = r7 - hi16f(l3);
  const unsigned q0 = cvt_pk(s0, s1), q1 = cvt_pk(s2, s3);
  const unsigned q2 = cvt_pk(s4, s5), q3 = cvt_pk(s6, s7);
  h  = __builtin_bit_cast(short8, (uint4x){h0, h1, h2, h3});
  lo = __builtin_bit_cast(short8, (uint4x){l0, l1, l2, l3});
  q  = __builtin_bit_cast(short8, (uint4x){q0, q1, q2, q3});
}

template <int KS>
__global__ __launch_bounds__(256) void gemm_mfma(const float* __restrict__ x,
    const unsigned short* __restrict__ Wh, const unsigned short* __restrict__ Wl,
    const unsigned short* __restrict__ Wq, float* __restrict__ part) {
  constexpr int NSTEP = (KDIM / KS) / 32;
  __shared__ float xs[2][4][2048];        // [buf][wave][64 rows x 32 k] 64 KB
  const int tid = (int)threadIdx.x;
  const int l   = tid & 63;
  const int wv  = tid >> 6;
  const int ks  = (int)blockIdx.x % KS;
  const int mt  = (int)blockIdx.x / KS;
  const int row0 = mt * 256 + wv * 64;
  const int kBeg = ks * (KDIM / KS);
  const int lr = l & 15;
  const int lk = l >> 4;

  f32x4 acc[4][4];
#pragma unroll
  for (int rt = 0; rt < 4; ++rt)
#pragma unroll
    for (int cb = 0; cb < 4; ++cb) acc[rt][cb] = (f32x4){0.f, 0.f, 0.f, 0.f};

  const int srow = l >> 3;
  const int sch  = (l & 7) ^ srow;
  const float* sp = x + (size_t)(row0 + srow) * KDIM + kBeg + sch * 4;

  const int m7  = lr & 7;
  const int c0o = ((lk * 2)     ^ m7) * 4;
  const int c1o = ((lk * 2 + 1) ^ m7) * 4;

  const size_t bbase = ((size_t)((kBeg >> 3) + lk)) * 64 + lr;
  const short8* BH = (const short8*)Wh + bbase;
  const short8* BL = (const short8*)Wl + bbase;
  const short8* BQ = (const short8*)Wq + bbase;

#define STAGE(buf, koff)                                                     \
  {                                                                          \
    _Pragma("unroll")                                                        \
    for (int i_ = 0; i_ < 8; ++i_) {                                         \
      __builtin_amdgcn_global_load_lds(                                      \
          sp + (size_t)(i_ * 8) * KDIM + (koff),                             \
          &xs[(buf)][wv][i_ * 256], 16, 0, 0);                               \
    }                                                                        \
  }

  STAGE(0, 0)
  __syncthreads();

  for (int s = 0; s < NSTEP; ++s) {
    const int buf = s & 1;
    if (s + 1 < NSTEP) STAGE(buf ^ 1, (s + 1) * 32)

    const int so = s * 256;
    short8 bh[4], bl[4], bq[4];
#pragma unroll
    for (int cb = 0; cb < 4; ++cb) {
      bh[cb] = BH[so + cb * 16];
      bl[cb] = BL[so + cb * 16];
      bq[cb] = BQ[so + cb * 16];
    }

    short8 ah[4], al[4], aq[4];
#pragma unroll
    for (int rt = 0; rt < 4; ++rt) {
      const float* pb = &xs[buf][wv][(rt * 16 + lr) * 32];
      float4 A0 = *(const float4*)(pb + c0o);
      float4 A1 = *(const float4*)(pb + c1o);
      cvt8pk(A0, A1, ah[rt], al[rt], aq[rt]);
    }

#pragma unroll
    for (int cb = 0; cb < 4; ++cb) {
#pragma unroll
      for (int rt = 0; rt < 4; ++rt) {
        acc[rt][cb] = MF(ah[rt], bh[cb], acc[rt][cb]);
        acc[rt][cb] = MF(ah[rt], bl[cb], acc[rt][cb]);
        acc[rt][cb] = MF(al[rt], bh[cb], acc[rt][cb]);
        acc[rt][cb] = MF(al[rt], bl[cb], acc[rt][cb]);
        acc[rt][cb] = MF(aq[rt], bh[cb], acc[rt][cb]);
        acc[rt][cb] = MF(ah[rt], bq[cb], acc[rt][cb]);
      }
    }

    __syncthreads();
  }
#undef STAGE

  float* pout = part + (size_t)ks * NE_TOT;
#pragma unroll
  for (int rt = 0; rt < 4; ++rt) {
    const int rb = row0 + rt * 16 + lk * 4;
#pragma unroll
    for (int r = 0; r < 4; ++r) {
#pragma unroll
      for (int cb = 0; cb < 4; ++cb)
        pout[(size_t)(rb + r) * 64 + cb * 16 + lr] = acc[rt][cb][r];
    }
  }
}

// ---------------------------------------------------------------------------
// Kernel 2: per-row gating -> TRANSPOSED outputs (unchanged — verified)
// ---------------------------------------------------------------------------
template <int KS>
__global__ __launch_bounds__(1024) void gate_rows(const float* __restrict__ part,
                                                  float* __restrict__ gatesT,
                                                  float* __restrict__ tamT) {
  __shared__ float gt[64][65];
  __shared__ float tt[64][65];
  const int tid  = (int)threadIdx.x;
  const int lane = tid & 63;
  const int wid  = tid >> 6;
  const int row0 = (int)blockIdx.x * 64;

#pragma unroll
  for (int r = 0; r < 4; ++r) {
    const int rloc = wid * 4 + r;
    const size_t base = (size_t)(row0 + rloc) * NEXP;

    float logit = 0.f;
#pragma unroll
    for (int s = 0; s < KS; ++s)
      logit += part[(size_t)s * NE_TOT + base + lane];

    float m = logit;
#pragma unroll
    for (int off = 32; off > 0; off >>= 1) m = fmaxf(m, __shfl_xor(m, off));
    float p = expf(logit - m);
    float sum = p;
#pragma unroll
    for (int off = 32; off > 0; off >>= 1) sum += __shfl_xor(sum, off);
    const float gate = p / sum;

    float g = gate;
    int idx = lane;
#pragma unroll
    for (int k = 2; k <= 64; k <<= 1) {
#pragma unroll
      for (int j = k >> 1; j > 0; j >>= 1) {
        float og = __shfl_xor(g, j);
        int   oi = __shfl_xor(idx, j);
        bool iLower     = (lane & j) == 0;
        bool wantFirst  = ((lane & k) == 0) ? iLower : !iLower;
        bool otherFirst = (og > g) || (og == g && oi < idx);
        if (otherFirst == wantFirst) { g = og; idx = oi; }
      }
    }

    float cum = g;
#pragma unroll
    for (int off = 1; off < 64; off <<= 1) {
      float t = __shfl_up(cum, off);
      if (lane >= off) cum += t;
    }
    const bool chosen = (lane == 0) || ((cum - g) < 0.5f);
    const float imp = chosen ? ((float)(NEXP - lane) + g) : 0.f;

    gt[rloc][lane] = gate;
    tt[rloc][idx]  = imp;
  }
  __syncthreads();

#pragma unroll
  for (int p = 0; p < 4; ++p) {
    const int e = p * 16 + wid;
    gatesT[(size_t)e * N_TOK + row0 + lane] = gt[lane][e];
    tamT  [(size_t)e * N_TOK + row0 + lane] = tt[lane][e];
  }
}

// ---------------------------------------------------------------------------
// Kernel 3: per-expert capacity truncation. R17 delta: the tam column is
//   staged ONCE into 64KB dynamic LDS (vcol); the 4 radix rounds, equals
//   scan, and final pass read vcol instead of re-reading global (cuts ~5
//   column re-reads on a 64-block grid). Selection logic byte-identical.
// ---------------------------------------------------------------------------
__global__ __launch_bounds__(1024) void expert_select(
    const float* __restrict__ gatesT, const float* __restrict__ tamT,
    float* __restrict__ me_sum, int* __restrict__ ce_cnt,
    float* __restrict__ combT) {
  extern __shared__ float vcol[];     // N_TOK floats (64 KB dynamic)
  __shared__ int   hist16[16][256];
  __shared__ int   hist[256];
  __shared__ float wsum[16];
  __shared__ int   wice[16];
  __shared__ int   wnnz[16];
  __shared__ int   wcnt[16];
  __shared__ unsigned sh_prefix;
  __shared__ int      sh_k;
  __shared__ int      sh_nnz;

  const int e    = (int)blockIdx.x;
  const int tid  = (int)threadIdx.x;
  const int lane = tid & 63;
  const int wid  = tid >> 6;
  const float* tcol = tamT   + (size_t)e * N_TOK;
  const float* gcol = gatesT + (size_t)e * N_TOK;

  float gsum = 0.f;
  int ccnt = 0, nnzl = 0;
#pragma unroll
  for (int k = 0; k < 4; ++k) {
    int i4 = tid + k * 1024;
    float4 tv = reinterpret_cast<const float4*>(tcol)[i4];
    float4 gv = reinterpret_cast<const float4*>(gcol)[i4];
    reinterpret_cast<float4*>(vcol)[i4] = tv;   // stage column in LDS
    gsum += gv.x + gv.y + gv.z + gv.w;
    ccnt += (tv.x > 64.f) + (tv.y > 64.f) + (tv.z > 64.f) + (tv.w > 64.f);
    nnzl += (tv.x != 0.f) + (tv.y != 0.f) + (tv.z != 0.f) + (tv.w != 0.f);
  }
#pragma unroll
  for (int off = 32; off > 0; off >>= 1) {
    gsum += __shfl_xor(gsum, off);
    ccnt += __shfl_xor(ccnt, off);
    nnzl += __shfl_xor(nnzl, off);
  }
  if (lane == 0) { wsum[wid] = gsum; wice[wid] = ccnt; wnnz[wid] = nnzl; }
  __syncthreads();
  if (tid == 0) {
    float t = 0.f; int c = 0, nz = 0;
    for (int w = 0; w < 16; ++w) { t += wsum[w]; c += wice[w]; nz += wnnz[w]; }
    me_sum[e] = t; ce_cnt[e] = c; sh_nnz = nz;
  }
  __syncthreads();
  const int nnz = sh_nnz;

  unsigned vstar = 0u;
  int meq = 0;
  if (nnz > CAP) {
    unsigned prefix = 0;
    int krem = CAP;
    for (int round = 0; round < 4; ++round) {
      const int shift = 24 - 8 * round;
      const unsigned maskAbove =
          (round == 0) ? 0u : (0xFFFFFFFFu << (shift + 8));
      for (int z = tid; z < 16 * 256; z += 1024) ((int*)hist16)[z] = 0;
      __syncthreads();
#pragma unroll
      for (int k = 0; k < 16; ++k) {
        unsigned u = __float_as_uint(vcol[tid + k * 1024]);
        if (u != 0u && (u & maskAbove) == prefix)
          atomicAdd(&hist16[wid][(u >> shift) & 255], 1);
      }
      __syncthreads();
      if (tid < 256) {
        int s = 0;
#pragma unroll
        for (int w = 0; w < 16; ++w) s += hist16[w][tid];
        hist[tid] = s;
      }
      __syncthreads();
      if (wid == 0) {
        int h0 = hist[lane * 4 + 0], h1 = hist[lane * 4 + 1];
        int h2 = hist[lane * 4 + 2], h3 = hist[lane * 4 + 3];
        int lsum = h0 + h1 + h2 + h3;
        int suf = lsum;
#pragma unroll
        for (int off = 1; off < 64; off <<= 1) {
          int t = __shfl_down(suf, off);
          if (lane + off < 64) suf += t;
        }
        int above = suf - lsum;
        int S3 = above + h3, S2 = S3 + h2, S1 = S2 + h1, S0 = S1 + h0;
        if (S0 >= krem && S1    < krem) { sh_prefix = prefix | ((unsigned)(lane*4+0) << shift); sh_k = krem - S1;    }
        if (S1 >= krem && S2    < krem) { sh_prefix = prefix | ((unsigned)(lane*4+1) << shift); sh_k = krem - S2;    }
        if (S2 >= krem && S3    < krem) { sh_prefix = prefix | ((unsigned)(lane*4+2) << shift); sh_k = krem - S3;    }
        if (S3 >= krem && above < krem) { sh_prefix = prefix | ((unsigned)(lane*4+3) << shift); sh_k = krem - above; }
      }
      __syncthreads();
      prefix = sh_prefix;
      krem   = sh_k;
      __syncthreads();
    }
    vstar = prefix;
    meq   = krem;
  }

  float4 tq[4];
#pragma unroll
  for (int q = 0; q < 4; ++q)
    tq[q] = reinterpret_cast<const float4*>(vcol)[tid * 4 + q];
  int cnt = 0;
#pragma unroll
  for (int q = 0; q < 4; ++q) {
    cnt += (__float_as_uint(tq[q].x) == vstar);
    cnt += (__float_as_uint(tq[q].y) == vstar);
    cnt += (__float_as_uint(tq[q].z) == vstar);
    cnt += (__float_as_uint(tq[q].w) == vstar);
  }
  int inc = cnt;
#pragma unroll
  for (int off = 1; off < 64; off <<= 1) {
    int t = __shfl_up(inc, off);
    if (lane >= off) inc += t;
  }
  if (lane == 63) wcnt[wid] = inc;
  __syncthreads();
  if (tid == 0) {
    int run = 0;
    for (int w = 0; w < 16; ++w) { int t = wcnt[w]; wcnt[w] = run; run += t; }
  }
  __syncthreads();
  int exc = (inc - cnt) + wcnt[wid];

  float* ccol = combT + (size_t)e * N_TOK;
#pragma unroll
  for (int q = 0; q < 4; ++q) {
    float4 gq = reinterpret_cast<const float4*>(gcol)[tid * 4 + q];
    float ov[4];
    const float tv[4] = {tq[q].x, tq[q].y, tq[q].z, tq[q].w};
    const float gv[4] = {gq.x, gq.y, gq.z, gq.w};
#pragma unroll
    for (int j = 0; j < 4; ++j) {
      unsigned u = __float_as_uint(tv[j]);
      bool keep;
      if (u == vstar) { keep = (exc < meq); ++exc; }
      else            { keep = (u > vstar); }
      ov[j] = (keep && u != 0u) ? gv[j] : 0.f;
    }
    reinterpret_cast<float4*>(ccol)[tid * 4 + q] =
        make_float4(ov[0], ov[1], ov[2], ov[3]);
  }
}

// ---------------------------------------------------------------------------
// Kernel 4: transpose combT[e][t] -> out[t][e]; block 0 also computes l_aux
// ---------------------------------------------------------------------------
__global__ __launch_bounds__(1024) void transpose_out(
    const float* __restrict__ combT, float* __restrict__ out1,
    const float* __restrict__ me_sum, const int* __restrict__ ce_cnt,
    float* __restrict__ out0) {
  __shared__ float tile[64][65];
  const int tid  = (int)threadIdx.x;
  const int lane = tid & 63;
  const int wid  = tid >> 6;
  const int tok0 = (int)blockIdx.x * 64;
#pragma unroll
  for (int p = 0; p < 4; ++p) {
    const int e = p * 16 + wid;
    tile[lane][e] = combT[(size_t)e * N_TOK + tok0 + lane];
  }
  __syncthreads();
#pragma unroll
  for (int q = 0; q < 4; ++q) {
    const int tok = q * 16 + wid;
    out1[(size_t)(tok0 + tok) * NEXP + lane] = tile[tok][lane];
  }
  if (blockIdx.x == 0 && wid == 0) {
    float v = (me_sum[lane] / (float)N_TOK) *
              ((float)ce_cnt[lane] / (float)N_TOK);
#pragma unroll
    for (int off = 32; off > 0; off >>= 1) v += __shfl_xor(v, off);
    if (lane == 0) out0[0] = v * (float)NEXP;
  }
}

// ---------------------------------------------------------------------------
extern "C" void kernel_launch(void* const* d_in, const int* in_sizes, int n_in,
                              void* d_out, int out_size, void* d_ws, size_t ws_size,
                              hipStream_t stream) {
  const float* x = (const float*)d_in[0];
  const float* W = (const float*)d_in[1];
  float* out = (float*)d_out;
  float* ws  = (float*)d_ws;

  // KS=8 needs (8+2)*4MB scratch; fall back to KS=4 if ws is smaller.
  const bool ks8 = ws_size >= (size_t)(8 + 2) * NE_TOT * 4 + 1024;

  const int KS = ks8 ? 8 : 4;
  float* part   = ws;                       // KS * 4 MB
  float* combT  = ws;                       // aliases part (dead by then)
  float* gatesT = ws + (size_t)KS * NE_TOT; // 4 MB
  float* tamT   = gatesT + NE_TOT;          // 4 MB
  float* me     = tamT + NE_TOT;
  int*   ce     = (int*)(me + 64);

  // W digit arrays (768 KB) live in the gatesT region: written by wdigits,
  // consumed by gemm_mfma, dead before gate_rows overwrites gatesT.
  unsigned short* Wh = (unsigned short*)gatesT;
  unsigned short* Wl = Wh + (size_t)NEXP * KDIM;
  unsigned short* Wq = Wl + (size_t)NEXP * KDIM;

  (void)hipFuncSetAttribute((const void*)expert_select,
                            hipFuncAttributeMaxDynamicSharedMemorySize,
                            N_TOK * 4);

  wdigits<<<(NEXP * KDIM) / 256, 256, 0, stream>>>(W, Wh, Wl, Wq);
  if (ks8) gemm_mfma<8><<<64 * 8, 256, 0, stream>>>(x, Wh, Wl, Wq, part);
  else     gemm_mfma<4><<<64 * 4, 256, 0, stream>>>(x, Wh, Wl, Wq, part);
  if (ks8) gate_rows<8><<<N_TOK / 64, 1024, 0, stream>>>(part, gatesT, tamT);
  else     gate_rows<4><<<N_TOK / 64, 1024, 0, stream>>>(part, gatesT, tamT);
  expert_select<<<NEXP, 1024, N_TOK * 4, stream>>>(gatesT, tamT, me, ce, combT);
  transpose_out<<<N_TOK / 64, 1024, 0, stream>>>(combT, out + 1, me, ce, out);
}

// Round 18
// 73.442 us; speedup vs baseline: 1.0747x; 1.0747x over previous
//
#include <hip/hip_runtime.h>
#include <cstdint>
#include <cstddef>

#define N_TOK  16384
#define NEXP   64
#define KDIM   2048
#define CAP    256   // ceil(16384/64 * 1.0) = 256
#define NE_TOT ((size_t)N_TOK * NEXP)

typedef __attribute__((ext_vector_type(8))) short short8;
typedef __attribute__((ext_vector_type(4))) float f32x4;
typedef __attribute__((ext_vector_type(4))) unsigned int uint4x;

__device__ __forceinline__ unsigned short bf16_rtn(float f) {
  unsigned u = __float_as_uint(f);
  u += 0x7FFFu + ((u >> 16) & 1u);
  return (unsigned short)(u >> 16);
}
__device__ __forceinline__ float bf16_f(unsigned short h) {
  return __uint_as_float((unsigned)h << 16);
}
__device__ __forceinline__ f32x4 MF(short8 a, short8 b, f32x4 c) {
  return __builtin_amdgcn_mfma_f32_16x16x32_bf16(a, b, c, 0, 0, 0);
}
// HW packed f32->bf16 RTNE (bit-identical to bf16_rtn; verified R6->R7)
__device__ __forceinline__ unsigned cvt_pk(float a, float b) {
  unsigned r;
  asm("v_cvt_pk_bf16_f32 %0, %1, %2" : "=v"(r) : "v"(a), "v"(b));
  return r;
}
__device__ __forceinline__ float lo16f(unsigned u) {
  return __uint_as_float(u << 16);
}
__device__ __forceinline__ float hi16f(unsigned u) {
  return __uint_as_float(u & 0xFFFF0000u);
}

// ---------------------------------------------------------------------------
// Kernel 0: split W into 3 bf16 digits, packed [k/8][col][8] (unchanged).
// ---------------------------------------------------------------------------
__global__ __launch_bounds__(256) void wdigits(const float* __restrict__ W,
    unsigned short* __restrict__ Wh, unsigned short* __restrict__ Wl,
    unsigned short* __restrict__ Wq) {
  const int e = (int)blockIdx.x * 256 + (int)threadIdx.x;  // 0..131071
  const int col = e >> 11;
  const int k   = e & 2047;
  const float w = W[(size_t)col * KDIM + k];
  const unsigned short h = bf16_rtn(w);
  const float r1 = w - bf16_f(h);
  const unsigned short lo = bf16_rtn(r1);
  const float r2 = r1 - bf16_f(lo);
  const unsigned short q = bf16_rtn(r2);
  const size_t idx = (size_t)(k >> 3) * 512 + (size_t)col * 8 + (k & 7);
  Wh[idx] = h; Wl[idx] = lo; Wq[idx] = q;
}

// ---------------------------------------------------------------------------
// Kernel 1: logits via 6-term split-bf16 MFMA.
//   R18 = R16 (verified 74.36us / absmax 0.0009765625) + ONE delta:
//   T4 counted-vmcnt replaces the per-step __syncthreads().
//   Legal because staging is WAVE-PRIVATE (wave wv writes/reads only
//   xs[*][wv]) — the barrier was pure drain overhead (compiler emits
//   vmcnt(0)+lgkmcnt(0)+s_barrier, locking 4 waves in lockstep each step).
//   Counted wait: each STAGE = 8 gload_lds; after issuing next step's 8,
//   s_waitcnt vmcnt(8) guarantees the previous 8 (current buffer) landed
//   while the new 8 stay in flight ACROSS the step boundary (m218 T4).
//   WAR safe: prior step's ds_reads complete before its MFMAs (compiler
//   lgkmcnt), which precede this STAGE in program order. sched_barrier(0)
//   after the wait per rule #18. Math/order untouched -> logits
//   bit-identical, absmax must repeat 0.0009765625 exactly.
// ---------------------------------------------------------------------------
__device__ __forceinline__ void cvt8pk(float4 a, float4 b,
                                       short8& h, short8& lo, short8& q) {
  const float f0 = a.x, f1 = a.y, f2 = a.z, f3 = a.w;
  const float f4 = b.x, f5 = b.y, f6 = b.z, f7 = b.w;
  const unsigned h0 = cvt_pk(f0, f1), h1 = cvt_pk(f2, f3);
  const unsigned h2 = cvt_pk(f4, f5), h3 = cvt_pk(f6, f7);
  const float r0 = f0 - lo16f(h0), r1 = f1 - hi16f(h0);
  const float r2 = f2 - lo16f(h1), r3 = f3 - hi16f(h1);
  const float r4 = f4 - lo16f(h2), r5 = f5 - hi16f(h2);
  const float r6 = f6 - lo16f(h3), r7 = f7 - hi16f(h3);
  const unsigned l0 = cvt_pk(r0, r1), l1 = cvt_pk(r2, r3);
  const unsigned l2 = cvt_pk(r4, r5), l3 = cvt_pk(r6, r7);
  const float s0 = r0 - lo16f(l0), s1 = r1 - hi16f(l0);
  const float s2 = r2 - lo16f(l1), s3 = r3 - hi16f(l1);
  const float s4 = r4 - lo16f(l2), s5 = r5 - hi16f(l2);
  const float s6 = r6 - lo16f(l3), s7 = r7 - hi16f(l3);
  const unsigned q0 = cvt_pk(s0, s1), q1 = cvt_pk(s2, s3);
  const unsigned q2 = cvt_pk(s4, s5), q3 = cvt_pk(s6, s7);
  h  = __builtin_bit_cast(short8, (uint4x){h0, h1, h2, h3});
  lo = __builtin_bit_cast(short8, (uint4x){l0, l1, l2, l3});
  q  = __builtin_bit_cast(short8, (uint4x){q0, q1, q2, q3});
}

template <int KS>
__global__ __launch_bounds__(256) void gemm_mfma(const float* __restrict__ x,
    const unsigned short* __restrict__ Wh, const unsigned short* __restrict__ Wl,
    const unsigned short* __restrict__ Wq, float* __restrict__ part) {
  constexpr int NSTEP = (KDIM / KS) / 32;
  __shared__ float xs[2][4][2048];        // [buf][wave][64 rows x 32 k] 64 KB
  const int tid = (int)threadIdx.x;
  const int l   = tid & 63;
  const int wv  = tid >> 6;
  const int ks  = (int)blockIdx.x % KS;
  const int mt  = (int)blockIdx.x / KS;
  const int row0 = mt * 256 + wv * 64;
  const int kBeg = ks * (KDIM / KS);
  const int lr = l & 15;
  const int lk = l >> 4;

  f32x4 acc[4][4];
#pragma unroll
  for (int rt = 0; rt < 4; ++rt)
#pragma unroll
    for (int cb = 0; cb < 4; ++cb) acc[rt][cb] = (f32x4){0.f, 0.f, 0.f, 0.f};

  const int srow = l >> 3;
  const int sch  = (l & 7) ^ srow;
  const float* sp = x + (size_t)(row0 + srow) * KDIM + kBeg + sch * 4;

  const int m7  = lr & 7;
  const int c0o = ((lk * 2)     ^ m7) * 4;
  const int c1o = ((lk * 2 + 1) ^ m7) * 4;

  const size_t bbase = ((size_t)((kBeg >> 3) + lk)) * 64 + lr;
  const short8* BH = (const short8*)Wh + bbase;
  const short8* BL = (const short8*)Wl + bbase;
  const short8* BQ = (const short8*)Wq + bbase;

#define STAGE(buf, koff)                                                     \
  {                                                                          \
    _Pragma("unroll")                                                        \
    for (int i_ = 0; i_ < 8; ++i_) {                                         \
      __builtin_amdgcn_global_load_lds(                                      \
          sp + (size_t)(i_ * 8) * KDIM + (koff),                             \
          &xs[(buf)][wv][i_ * 256], 16, 0, 0);                               \
    }                                                                        \
  }

  STAGE(0, 0)   // 8 loads in flight; waited inside loop via counted vmcnt

  for (int s = 0; s < NSTEP; ++s) {
    const int buf = s & 1;
    // issue next step's 8 loads, then counted-wait for current buffer:
    // vmcnt(8) = previous stage's 8 oldest done, new 8 stay in flight.
    if (s + 1 < NSTEP) {
      STAGE(buf ^ 1, (s + 1) * 32)
      asm volatile("s_waitcnt vmcnt(8)" ::: "memory");
    } else {
      asm volatile("s_waitcnt vmcnt(0)" ::: "memory");
    }
    __builtin_amdgcn_sched_barrier(0);   // rule #18: pin ds_reads after wait

    const int so = s * 256;
    short8 bh[4], bl[4], bq[4];
#pragma unroll
    for (int cb = 0; cb < 4; ++cb) {
      bh[cb] = BH[so + cb * 16];
      bl[cb] = BL[so + cb * 16];
      bq[cb] = BQ[so + cb * 16];
    }

    short8 ah[4], al[4], aq[4];
#pragma unroll
    for (int rt = 0; rt < 4; ++rt) {
      const float* pb = &xs[buf][wv][(rt * 16 + lr) * 32];
      float4 A0 = *(const float4*)(pb + c0o);
      float4 A1 = *(const float4*)(pb + c1o);
      cvt8pk(A0, A1, ah[rt], al[rt], aq[rt]);
    }

#pragma unroll
    for (int cb = 0; cb < 4; ++cb) {
#pragma unroll
      for (int rt = 0; rt < 4; ++rt) {
        acc[rt][cb] = MF(ah[rt], bh[cb], acc[rt][cb]);
        acc[rt][cb] = MF(ah[rt], bl[cb], acc[rt][cb]);
        acc[rt][cb] = MF(al[rt], bh[cb], acc[rt][cb]);
        acc[rt][cb] = MF(al[rt], bl[cb], acc[rt][cb]);
        acc[rt][cb] = MF(aq[rt], bh[cb], acc[rt][cb]);
        acc[rt][cb] = MF(ah[rt], bq[cb], acc[rt][cb]);
      }
    }
  }
#undef STAGE

  float* pout = part + (size_t)ks * NE_TOT;
#pragma unroll
  for (int rt = 0; rt < 4; ++rt) {
    const int rb = row0 + rt * 16 + lk * 4;
#pragma unroll
    for (int r = 0; r < 4; ++r) {
#pragma unroll
      for (int cb = 0; cb < 4; ++cb)
        pout[(size_t)(rb + r) * 64 + cb * 16 + lr] = acc[rt][cb][r];
    }
  }
}

// ---------------------------------------------------------------------------
// Kernel 2: per-row gating -> TRANSPOSED outputs (unchanged — verified)
// ---------------------------------------------------------------------------
template <int KS>
__global__ __launch_bounds__(1024) void gate_rows(const float* __restrict__ part,
                                                  float* __restrict__ gatesT,
                                                  float* __restrict__ tamT) {
  __shared__ float gt[64][65];
  __shared__ float tt[64][65];
  const int tid  = (int)threadIdx.x;
  const int lane = tid & 63;
  const int wid  = tid >> 6;
  const int row0 = (int)blockIdx.x * 64;

#pragma unroll
  for (int r = 0; r < 4; ++r) {
    const int rloc = wid * 4 + r;
    const size_t base = (size_t)(row0 + rloc) * NEXP;

    float logit = 0.f;
#pragma unroll
    for (int s = 0; s < KS; ++s)
      logit += part[(size_t)s * NE_TOT + base + lane];

    float m = logit;
#pragma unroll
    for (int off = 32; off > 0; off >>= 1) m = fmaxf(m, __shfl_xor(m, off));
    float p = expf(logit - m);
    float sum = p;
#pragma unroll
    for (int off = 32; off > 0; off >>= 1) sum += __shfl_xor(sum, off);
    const float gate = p / sum;

    float g = gate;
    int idx = lane;
#pragma unroll
    for (int k = 2; k <= 64; k <<= 1) {
#pragma unroll
      for (int j = k >> 1; j > 0; j >>= 1) {
        float og = __shfl_xor(g, j);
        int   oi = __shfl_xor(idx, j);
        bool iLower     = (lane & j) == 0;
        bool wantFirst  = ((lane & k) == 0) ? iLower : !iLower;
        bool otherFirst = (og > g) || (og == g && oi < idx);
        if (otherFirst == wantFirst) { g = og; idx = oi; }
      }
    }

    float cum = g;
#pragma unroll
    for (int off = 1; off < 64; off <<= 1) {
      float t = __shfl_up(cum, off);
      if (lane >= off) cum += t;
    }
    const bool chosen = (lane == 0) || ((cum - g) < 0.5f);
    const float imp = chosen ? ((float)(NEXP - lane) + g) : 0.f;

    gt[rloc][lane] = gate;
    tt[rloc][idx]  = imp;
  }
  __syncthreads();

#pragma unroll
  for (int p = 0; p < 4; ++p) {
    const int e = p * 16 + wid;
    gatesT[(size_t)e * N_TOK + row0 + lane] = gt[lane][e];
    tamT  [(size_t)e * N_TOK + row0 + lane] = tt[lane][e];
  }
}

// ---------------------------------------------------------------------------
// Kernel 3: per-expert capacity truncation (R16 version — verified; R17's
//   LDS staging reverted, it regressed)
// ---------------------------------------------------------------------------
__global__ __launch_bounds__(1024) void expert_select(
    const float* __restrict__ gatesT, const float* __restrict__ tamT,
    float* __restrict__ me_sum, int* __restrict__ ce_cnt,
    float* __restrict__ combT) {
  __shared__ int   hist16[16][256];
  __shared__ int   hist[256];
  __shared__ float wsum[16];
  __shared__ int   wice[16];
  __shared__ int   wnnz[16];
  __shared__ int   wcnt[16];
  __shared__ unsigned sh_prefix;
  __shared__ int      sh_k;
  __shared__ int      sh_nnz;

  const int e    = (int)blockIdx.x;
  const int tid  = (int)threadIdx.x;
  const int lane = tid & 63;
  const int wid  = tid >> 6;
  const float* tcol = tamT   + (size_t)e * N_TOK;
  const float* gcol = gatesT + (size_t)e * N_TOK;

  float gsum = 0.f;
  int ccnt = 0, nnzl = 0;
#pragma unroll
  for (int k = 0; k < 4; ++k) {
    int i4 = tid + k * 1024;
    float4 tv = reinterpret_cast<const float4*>(tcol)[i4];
    float4 gv = reinterpret_cast<const float4*>(gcol)[i4];
    gsum += gv.x + gv.y + gv.z + gv.w;
    ccnt += (tv.x > 64.f) + (tv.y > 64.f) + (tv.z > 64.f) + (tv.w > 64.f);
    nnzl += (tv.x != 0.f) + (tv.y != 0.f) + (tv.z != 0.f) + (tv.w != 0.f);
  }
#pragma unroll
  for (int off = 32; off > 0; off >>= 1) {
    gsum += __shfl_xor(gsum, off);
    ccnt += __shfl_xor(ccnt, off);
    nnzl += __shfl_xor(nnzl, off);
  }
  if (lane == 0) { wsum[wid] = gsum; wice[wid] = ccnt; wnnz[wid] = nnzl; }
  __syncthreads();
  if (tid == 0) {
    float t = 0.f; int c = 0, nz = 0;
    for (int w = 0; w < 16; ++w) { t += wsum[w]; c += wice[w]; nz += wnnz[w]; }
    me_sum[e] = t; ce_cnt[e] = c; sh_nnz = nz;
  }
  __syncthreads();
  const int nnz = sh_nnz;

  unsigned vstar = 0u;
  int meq = 0;
  if (nnz > CAP) {
    unsigned prefix = 0;
    int krem = CAP;
    for (int round = 0; round < 4; ++round) {
      const int shift = 24 - 8 * round;
      const unsigned maskAbove =
          (round == 0) ? 0u : (0xFFFFFFFFu << (shift + 8));
      for (int z = tid; z < 16 * 256; z += 1024) ((int*)hist16)[z] = 0;
      __syncthreads();
#pragma unroll
      for (int k = 0; k < 16; ++k) {
        unsigned u = __float_as_uint(tcol[tid + k * 1024]);
        if (u != 0u && (u & maskAbove) == prefix)
          atomicAdd(&hist16[wid][(u >> shift) & 255], 1);
      }
      __syncthreads();
      if (tid < 256) {
        int s = 0;
#pragma unroll
        for (int w = 0; w < 16; ++w) s += hist16[w][tid];
        hist[tid] = s;
      }
      __syncthreads();
      if (wid == 0) {
        int h0 = hist[lane * 4 + 0], h1 = hist[lane * 4 + 1];
        int h2 = hist[lane * 4 + 2], h3 = hist[lane * 4 + 3];
        int lsum = h0 + h1 + h2 + h3;
        int suf = lsum;
#pragma unroll
        for (int off = 1; off < 64; off <<= 1) {
          int t = __shfl_down(suf, off);
          if (lane + off < 64) suf += t;
        }
        int above = suf - lsum;
        int S3 = above + h3, S2 = S3 + h2, S1 = S2 + h1, S0 = S1 + h0;
        if (S0 >= krem && S1    < krem) { sh_prefix = prefix | ((unsigned)(lane*4+0) << shift); sh_k = krem - S1;    }
        if (S1 >= krem && S2    < krem) { sh_prefix = prefix | ((unsigned)(lane*4+1) << shift); sh_k = krem - S2;    }
        if (S2 >= krem && S3    < krem) { sh_prefix = prefix | ((unsigned)(lane*4+2) << shift); sh_k = krem - S3;    }
        if (S3 >= krem && above < krem) { sh_prefix = prefix | ((unsigned)(lane*4+3) << shift); sh_k = krem - above; }
      }
      __syncthreads();
      prefix = sh_prefix;
      krem   = sh_k;
      __syncthreads();
    }
    vstar = prefix;
    meq   = krem;
  }

  float4 tq[4];
#pragma unroll
  for (int q = 0; q < 4; ++q)
    tq[q] = reinterpret_cast<const float4*>(tcol)[tid * 4 + q];
  int cnt = 0;
#pragma unroll
  for (int q = 0; q < 4; ++q) {
    cnt += (__float_as_uint(tq[q].x) == vstar);
    cnt += (__float_as_uint(tq[q].y) == vstar);
    cnt += (__float_as_uint(tq[q].z) == vstar);
    cnt += (__float_as_uint(tq[q].w) == vstar);
  }
  int inc = cnt;
#pragma unroll
  for (int off = 1; off < 64; off <<= 1) {
    int t = __shfl_up(inc, off);
    if (lane >= off) inc += t;
  }
  if (lane == 63) wcnt[wid] = inc;
  __syncthreads();
  if (tid == 0) {
    int run = 0;
    for (int w = 0; w < 16; ++w) { int t = wcnt[w]; wcnt[w] = run; run += t; }
  }
  __syncthreads();
  int exc = (inc - cnt) + wcnt[wid];

  float* ccol = combT + (size_t)e * N_TOK;
#pragma unroll
  for (int q = 0; q < 4; ++q) {
    float4 gq = reinterpret_cast<const float4*>(gcol)[tid * 4 + q];
    float ov[4];
    const float tv[4] = {tq[q].x, tq[q].y, tq[q].z, tq[q].w};
    const float gv[4] = {gq.x, gq.y, gq.z, gq.w};
#pragma unroll
    for (int j = 0; j < 4; ++j) {
      unsigned u = __float_as_uint(tv[j]);
      bool keep;
      if (u == vstar) { keep = (exc < meq); ++exc; }
      else            { keep = (u > vstar); }
      ov[j] = (keep && u != 0u) ? gv[j] : 0.f;
    }
    reinterpret_cast<float4*>(ccol)[tid * 4 + q] =
        make_float4(ov[0], ov[1], ov[2], ov[3]);
  }
}

// ---------------------------------------------------------------------------
// Kernel 4: transpose combT[e][t] -> out[t][e]; block 0 also computes l_aux
// ---------------------------------------------------------------------------
__global__ __launch_bounds__(1024) void transpose_out(
    const float* __restrict__ combT, float* __restrict__ out1,
    const float* __restrict__ me_sum, const int* __restrict__ ce_cnt,
    float* __restrict__ out0) {
  __shared__ float tile[64][65];
  const int tid  = (int)threadIdx.x;
  const int lane = tid & 63;
  const int wid  = tid >> 6;
  const int tok0 = (int)blockIdx.x * 64;
#pragma unroll
  for (int p = 0; p < 4; ++p) {
    const int e = p * 16 + wid;
    tile[lane][e] = combT[(size_t)e * N_TOK + tok0 + lane];
  }
  __syncthreads();
#pragma unroll
  for (int q = 0; q < 4; ++q) {
    const int tok = q * 16 + wid;
    out1[(size_t)(tok0 + tok) * NEXP + lane] = tile[tok][lane];
  }
  if (blockIdx.x == 0 && wid == 0) {
    float v = (me_sum[lane] / (float)N_TOK) *
              ((float)ce_cnt[lane] / (float)N_TOK);
#pragma unroll
    for (int off = 32; off > 0; off >>= 1) v += __shfl_xor(v, off);
    if (lane == 0) out0[0] = v * (float)NEXP;
  }
}

// ---------------------------------------------------------------------------
extern "C" void kernel_launch(void* const* d_in, const int* in_sizes, int n_in,
                              void* d_out, int out_size, void* d_ws, size_t ws_size,
                              hipStream_t stream) {
  const float* x = (const float*)d_in[0];
  const float* W = (const float*)d_in[1];
  float* out = (float*)d_out;
  float* ws  = (float*)d_ws;

  // KS=8 needs (8+2)*4MB scratch; fall back to KS=4 if ws is smaller.
  const bool ks8 = ws_size >= (size_t)(8 + 2) * NE_TOT * 4 + 1024;

  const int KS = ks8 ? 8 : 4;
  float* part   = ws;                       // KS * 4 MB
  float* combT  = ws;                       // aliases part (dead by then)
  float* gatesT = ws + (size_t)KS * NE_TOT; // 4 MB
  float* tamT   = gatesT + NE_TOT;          // 4 MB
  float* me     = tamT + NE_TOT;
  int*   ce     = (int*)(me + 64);

  // W digit arrays (768 KB) live in the gatesT region: written by wdigits,
  // consumed by gemm_mfma, dead before gate_rows overwrites gatesT.
  unsigned short* Wh = (unsigned short*)gatesT;
  unsigned short* Wl = Wh + (size_t)NEXP * KDIM;
  unsigned short* Wq = Wl + (size_t)NEXP * KDIM;

  wdigits<<<(NEXP * KDIM) / 256, 256, 0, stream>>>(W, Wh, Wl, Wq);
  if (ks8) gemm_mfma<8><<<64 * 8, 256, 0, stream>>>(x, Wh, Wl, Wq, part);
  else     gemm_mfma<4><<<64 * 4, 256, 0, stream>>>(x, Wh, Wl, Wq, part);
  if (ks8) gate_rows<8><<<N_TOK / 64, 1024, 0, stream>>>(part, gatesT, tamT);
  else     gate_rows<4><<<N_TOK / 64, 1024, 0, stream>>>(part, gatesT, tamT);
  expert_select<<<NEXP, 1024, 0, stream>>>(gatesT, tamT, me, ce, combT);
  transpose_out<<<N_TOK / 64, 1024, 0, stream>>>(combT, out + 1, me, ce, out);
}

// Round 19
// 72.767 us; speedup vs baseline: 1.0847x; 1.0093x over previous
//
#include <hip/hip_runtime.h>
#include <cstdint>
#include <cstddef>

#define N_TOK  16384
#define NEXP   64
#define KDIM   2048
#define CAP    256   // ceil(16384/64 * 1.0) = 256
#define NE_TOT ((size_t)N_TOK * NEXP)

typedef __attribute__((ext_vector_type(8))) short short8;
typedef __attribute__((ext_vector_type(4))) float f32x4;
typedef __attribute__((ext_vector_type(4))) unsigned int uint4x;

__device__ __forceinline__ unsigned short bf16_rtn(float f) {
  unsigned u = __float_as_uint(f);
  u += 0x7FFFu + ((u >> 16) & 1u);
  return (unsigned short)(u >> 16);
}
__device__ __forceinline__ float bf16_f(unsigned short h) {
  return __uint_as_float((unsigned)h << 16);
}
__device__ __forceinline__ f32x4 MF(short8 a, short8 b, f32x4 c) {
  return __builtin_amdgcn_mfma_f32_16x16x32_bf16(a, b, c, 0, 0, 0);
}
// HW packed f32->bf16 RTNE (bit-identical to bf16_rtn; verified R6->R7)
__device__ __forceinline__ unsigned cvt_pk(float a, float b) {
  unsigned r;
  asm("v_cvt_pk_bf16_f32 %0, %1, %2" : "=v"(r) : "v"(a), "v"(b));
  return r;
}
__device__ __forceinline__ float lo16f(unsigned u) {
  return __uint_as_float(u << 16);
}
__device__ __forceinline__ float hi16f(unsigned u) {
  return __uint_as_float(u & 0xFFFF0000u);
}

// ---------------------------------------------------------------------------
// Kernel 0: split W into 3 bf16 digits, packed [k/8][col][8] (unchanged).
// ---------------------------------------------------------------------------
__global__ __launch_bounds__(256) void wdigits(const float* __restrict__ W,
    unsigned short* __restrict__ Wh, unsigned short* __restrict__ Wl,
    unsigned short* __restrict__ Wq) {
  const int e = (int)blockIdx.x * 256 + (int)threadIdx.x;  // 0..131071
  const int col = e >> 11;
  const int k   = e & 2047;
  const float w = W[(size_t)col * KDIM + k];
  const unsigned short h = bf16_rtn(w);
  const float r1 = w - bf16_f(h);
  const unsigned short lo = bf16_rtn(r1);
  const float r2 = r1 - bf16_f(lo);
  const unsigned short q = bf16_rtn(r2);
  const size_t idx = (size_t)(k >> 3) * 512 + (size_t)col * 8 + (k & 7);
  Wh[idx] = h; Wl[idx] = lo; Wq[idx] = q;
}

// ---------------------------------------------------------------------------
// Kernel 1: logits via 6-term split-bf16 MFMA.
//   R19 = R18 (verified best 73.44us) + ONE delta: vmem QUEUE-ORDER fix.
//   vmcnt retires FIFO in issue order. R18 issued STAGE(8) then B(12):
//   B loads were the newest queue entries, so the compiler's wait for B
//   before the MFMAs drained the staging loads too (effective vmcnt(0)
//   every step — counted pipeline silently defeated; explains the ~1us
//   gain). R19 issues B(12) FIRST, then STAGE(8), then waits vmcnt(20)
//   (prev stage's 8 = oldest retired; 12 B + 8 new staging may remain).
//   The compiler's B-wait then lands at vmcnt(8), leaving the staging
//   loads in flight ACROSS the MFMA block. sched_barrier(0) pins B-before-
//   STAGE issue order and the post-wait region (rule #18).
//   Loads, MFMA nest, term/k order unchanged -> logits bit-identical,
//   absmax must repeat 0.0009765625 exactly.
// ---------------------------------------------------------------------------
__device__ __forceinline__ void cvt8pk(float4 a, float4 b,
                                       short8& h, short8& lo, short8& q) {
  const float f0 = a.x, f1 = a.y, f2 = a.z, f3 = a.w;
  const float f4 = b.x, f5 = b.y, f6 = b.z, f7 = b.w;
  const unsigned h0 = cvt_pk(f0, f1), h1 = cvt_pk(f2, f3);
  const unsigned h2 = cvt_pk(f4, f5), h3 = cvt_pk(f6, f7);
  const float r0 = f0 - lo16f(h0), r1 = f1 - hi16f(h0);
  const float r2 = f2 - lo16f(h1), r3 = f3 - hi16f(h1);
  const float r4 = f4 - lo16f(h2), r5 = f5 - hi16f(h2);
  const float r6 = f6 - lo16f(h3), r7 = f7 - hi16f(h3);
  const unsigned l0 = cvt_pk(r0, r1), l1 = cvt_pk(r2, r3);
  const unsigned l2 = cvt_pk(r4, r5), l3 = cvt_pk(r6, r7);
  const float s0 = r0 - lo16f(l0), s1 = r1 - hi16f(l0);
  const float s2 = r2 - lo16f(l1), s3 = r3 - hi16f(l1);
  const float s4 = r4 - lo16f(l2), s5 = r5 - hi16f(l2);
  const float s6 = r6 - lo16f(l3), s7 = r7 - hi16f(l3);
  const unsigned q0 = cvt_pk(s0, s1), q1 = cvt_pk(s2, s3);
  const unsigned q2 = cvt_pk(s4, s5), q3 = cvt_pk(s6, s7);
  h  = __builtin_bit_cast(short8, (uint4x){h0, h1, h2, h3});
  lo = __builtin_bit_cast(short8, (uint4x){l0, l1, l2, l3});
  q  = __builtin_bit_cast(short8, (uint4x){q0, q1, q2, q3});
}

template <int KS>
__global__ __launch_bounds__(256) void gemm_mfma(const float* __restrict__ x,
    const unsigned short* __restrict__ Wh, const unsigned short* __restrict__ Wl,
    const unsigned short* __restrict__ Wq, float* __restrict__ part) {
  constexpr int NSTEP = (KDIM / KS) / 32;
  __shared__ float xs[2][4][2048];        // [buf][wave][64 rows x 32 k] 64 KB
  const int tid = (int)threadIdx.x;
  const int l   = tid & 63;
  const int wv  = tid >> 6;
  const int ks  = (int)blockIdx.x % KS;
  const int mt  = (int)blockIdx.x / KS;
  const int row0 = mt * 256 + wv * 64;
  const int kBeg = ks * (KDIM / KS);
  const int lr = l & 15;
  const int lk = l >> 4;

  f32x4 acc[4][4];
#pragma unroll
  for (int rt = 0; rt < 4; ++rt)
#pragma unroll
    for (int cb = 0; cb < 4; ++cb) acc[rt][cb] = (f32x4){0.f, 0.f, 0.f, 0.f};

  const int srow = l >> 3;
  const int sch  = (l & 7) ^ srow;
  const float* sp = x + (size_t)(row0 + srow) * KDIM + kBeg + sch * 4;

  const int m7  = lr & 7;
  const int c0o = ((lk * 2)     ^ m7) * 4;
  const int c1o = ((lk * 2 + 1) ^ m7) * 4;

  const size_t bbase = ((size_t)((kBeg >> 3) + lk)) * 64 + lr;
  const short8* BH = (const short8*)Wh + bbase;
  const short8* BL = (const short8*)Wl + bbase;
  const short8* BQ = (const short8*)Wq + bbase;

#define STAGE(buf, koff)                                                     \
  {                                                                          \
    _Pragma("unroll")                                                        \
    for (int i_ = 0; i_ < 8; ++i_) {                                         \
      __builtin_amdgcn_global_load_lds(                                      \
          sp + (size_t)(i_ * 8) * KDIM + (koff),                             \
          &xs[(buf)][wv][i_ * 256], 16, 0, 0);                               \
    }                                                                        \
  }

  STAGE(0, 0)   // 8 loads in flight; waited inside loop via counted vmcnt

  for (int s = 0; s < NSTEP; ++s) {
    const int buf = s & 1;

    // B loads FIRST -> they sit OLDER than the new staging loads in the
    // vmem queue, so the compiler's B-wait resolves at vmcnt(8) without
    // draining the staging pipeline.
    const int so = s * 256;
    short8 bh[4], bl[4], bq[4];
#pragma unroll
    for (int cb = 0; cb < 4; ++cb) {
      bh[cb] = BH[so + cb * 16];
      bl[cb] = BL[so + cb * 16];
      bq[cb] = BQ[so + cb * 16];
    }
    __builtin_amdgcn_sched_barrier(0);   // pin: B issued before STAGE

    // issue next step's 8 staging loads, then counted-wait for current buf:
    // queue = [prev8(oldest)][B12][new8] -> vmcnt(20) retires prev8 only.
    if (s + 1 < NSTEP) {
      STAGE(buf ^ 1, (s + 1) * 32)
      asm volatile("s_waitcnt vmcnt(20)" ::: "memory");
    } else {
      asm volatile("s_waitcnt vmcnt(12)" ::: "memory");
    }
    __builtin_amdgcn_sched_barrier(0);   // rule #18: pin ds_reads after wait

    short8 ah[4], al[4], aq[4];
#pragma unroll
    for (int rt = 0; rt < 4; ++rt) {
      const float* pb = &xs[buf][wv][(rt * 16 + lr) * 32];
      float4 A0 = *(const float4*)(pb + c0o);
      float4 A1 = *(const float4*)(pb + c1o);
      cvt8pk(A0, A1, ah[rt], al[rt], aq[rt]);
    }

#pragma unroll
    for (int cb = 0; cb < 4; ++cb) {
#pragma unroll
      for (int rt = 0; rt < 4; ++rt) {
        acc[rt][cb] = MF(ah[rt], bh[cb], acc[rt][cb]);
        acc[rt][cb] = MF(ah[rt], bl[cb], acc[rt][cb]);
        acc[rt][cb] = MF(al[rt], bh[cb], acc[rt][cb]);
        acc[rt][cb] = MF(al[rt], bl[cb], acc[rt][cb]);
        acc[rt][cb] = MF(aq[rt], bh[cb], acc[rt][cb]);
        acc[rt][cb] = MF(ah[rt], bq[cb], acc[rt][cb]);
      }
    }
  }
#undef STAGE

  float* pout = part + (size_t)ks * NE_TOT;
#pragma unroll
  for (int rt = 0; rt < 4; ++rt) {
    const int rb = row0 + rt * 16 + lk * 4;
#pragma unroll
    for (int r = 0; r < 4; ++r) {
#pragma unroll
      for (int cb = 0; cb < 4; ++cb)
        pout[(size_t)(rb + r) * 64 + cb * 16 + lr] = acc[rt][cb][r];
    }
  }
}

// ---------------------------------------------------------------------------
// Kernel 2: per-row gating -> TRANSPOSED outputs (unchanged — verified)
// ---------------------------------------------------------------------------
template <int KS>
__global__ __launch_bounds__(1024) void gate_rows(const float* __restrict__ part,
                                                  float* __restrict__ gatesT,
                                                  float* __restrict__ tamT) {
  __shared__ float gt[64][65];
  __shared__ float tt[64][65];
  const int tid  = (int)threadIdx.x;
  const int lane = tid & 63;
  const int wid  = tid >> 6;
  const int row0 = (int)blockIdx.x * 64;

#pragma unroll
  for (int r = 0; r < 4; ++r) {
    const int rloc = wid * 4 + r;
    const size_t base = (size_t)(row0 + rloc) * NEXP;

    float logit = 0.f;
#pragma unroll
    for (int s = 0; s < KS; ++s)
      logit += part[(size_t)s * NE_TOT + base + lane];

    float m = logit;
#pragma unroll
    for (int off = 32; off > 0; off >>= 1) m = fmaxf(m, __shfl_xor(m, off));
    float p = expf(logit - m);
    float sum = p;
#pragma unroll
    for (int off = 32; off > 0; off >>= 1) sum += __shfl_xor(sum, off);
    const float gate = p / sum;

    float g = gate;
    int idx = lane;
#pragma unroll
    for (int k = 2; k <= 64; k <<= 1) {
#pragma unroll
      for (int j = k >> 1; j > 0; j >>= 1) {
        float og = __shfl_xor(g, j);
        int   oi = __shfl_xor(idx, j);
        bool iLower     = (lane & j) == 0;
        bool wantFirst  = ((lane & k) == 0) ? iLower : !iLower;
        bool otherFirst = (og > g) || (og == g && oi < idx);
        if (otherFirst == wantFirst) { g = og; idx = oi; }
      }
    }

    float cum = g;
#pragma unroll
    for (int off = 1; off < 64; off <<= 1) {
      float t = __shfl_up(cum, off);
      if (lane >= off) cum += t;
    }
    const bool chosen = (lane == 0) || ((cum - g) < 0.5f);
    const float imp = chosen ? ((float)(NEXP - lane) + g) : 0.f;

    gt[rloc][lane] = gate;
    tt[rloc][idx]  = imp;
  }
  __syncthreads();

#pragma unroll
  for (int p = 0; p < 4; ++p) {
    const int e = p * 16 + wid;
    gatesT[(size_t)e * N_TOK + row0 + lane] = gt[lane][e];
    tamT  [(size_t)e * N_TOK + row0 + lane] = tt[lane][e];
  }
}

// ---------------------------------------------------------------------------
// Kernel 3: per-expert capacity truncation (R16 version — verified)
// ---------------------------------------------------------------------------
__global__ __launch_bounds__(1024) void expert_select(
    const float* __restrict__ gatesT, const float* __restrict__ tamT,
    float* __restrict__ me_sum, int* __restrict__ ce_cnt,
    float* __restrict__ combT) {
  __shared__ int   hist16[16][256];
  __shared__ int   hist[256];
  __shared__ float wsum[16];
  __shared__ int   wice[16];
  __shared__ int   wnnz[16];
  __shared__ int   wcnt[16];
  __shared__ unsigned sh_prefix;
  __shared__ int      sh_k;
  __shared__ int      sh_nnz;

  const int e    = (int)blockIdx.x;
  const int tid  = (int)threadIdx.x;
  const int lane = tid & 63;
  const int wid  = tid >> 6;
  const float* tcol = tamT   + (size_t)e * N_TOK;
  const float* gcol = gatesT + (size_t)e * N_TOK;

  float gsum = 0.f;
  int ccnt = 0, nnzl = 0;
#pragma unroll
  for (int k = 0; k < 4; ++k) {
    int i4 = tid + k * 1024;
    float4 tv = reinterpret_cast<const float4*>(tcol)[i4];
    float4 gv = reinterpret_cast<const float4*>(gcol)[i4];
    gsum += gv.x + gv.y + gv.z + gv.w;
    ccnt += (tv.x > 64.f) + (tv.y > 64.f) + (tv.z > 64.f) + (tv.w > 64.f);
    nnzl += (tv.x != 0.f) + (tv.y != 0.f) + (tv.z != 0.f) + (tv.w != 0.f);
  }
#pragma unroll
  for (int off = 32; off > 0; off >>= 1) {
    gsum += __shfl_xor(gsum, off);
    ccnt += __shfl_xor(ccnt, off);
    nnzl += __shfl_xor(nnzl, off);
  }
  if (lane == 0) { wsum[wid] = gsum; wice[wid] = ccnt; wnnz[wid] = nnzl; }
  __syncthreads();
  if (tid == 0) {
    float t = 0.f; int c = 0, nz = 0;
    for (int w = 0; w < 16; ++w) { t += wsum[w]; c += wice[w]; nz += wnnz[w]; }
    me_sum[e] = t; ce_cnt[e] = c; sh_nnz = nz;
  }
  __syncthreads();
  const int nnz = sh_nnz;

  unsigned vstar = 0u;
  int meq = 0;
  if (nnz > CAP) {
    unsigned prefix = 0;
    int krem = CAP;
    for (int round = 0; round < 4; ++round) {
      const int shift = 24 - 8 * round;
      const unsigned maskAbove =
          (round == 0) ? 0u : (0xFFFFFFFFu << (shift + 8));
      for (int z = tid; z < 16 * 256; z += 1024) ((int*)hist16)[z] = 0;
      __syncthreads();
#pragma unroll
      for (int k = 0; k < 16; ++k) {
        unsigned u = __float_as_uint(tcol[tid + k * 1024]);
        if (u != 0u && (u & maskAbove) == prefix)
          atomicAdd(&hist16[wid][(u >> shift) & 255], 1);
      }
      __syncthreads();
      if (tid < 256) {
        int s = 0;
#pragma unroll
        for (int w = 0; w < 16; ++w) s += hist16[w][tid];
        hist[tid] = s;
      }
      __syncthreads();
      if (wid == 0) {
        int h0 = hist[lane * 4 + 0], h1 = hist[lane * 4 + 1];
        int h2 = hist[lane * 4 + 2], h3 = hist[lane * 4 + 3];
        int lsum = h0 + h1 + h2 + h3;
        int suf = lsum;
#pragma unroll
        for (int off = 1; off < 64; off <<= 1) {
          int t = __shfl_down(suf, off);
          if (lane + off < 64) suf += t;
        }
        int above = suf - lsum;
        int S3 = above + h3, S2 = S3 + h2, S1 = S2 + h1, S0 = S1 + h0;
        if (S0 >= krem && S1    < krem) { sh_prefix = prefix | ((unsigned)(lane*4+0) << shift); sh_k = krem - S1;    }
        if (S1 >= krem && S2    < krem) { sh_prefix = prefix | ((unsigned)(lane*4+1) << shift); sh_k = krem - S2;    }
        if (S2 >= krem && S3    < krem) { sh_prefix = prefix | ((unsigned)(lane*4+2) << shift); sh_k = krem - S3;    }
        if (S3 >= krem && above < krem) { sh_prefix = prefix | ((unsigned)(lane*4+3) << shift); sh_k = krem - above; }
      }
      __syncthreads();
      prefix = sh_prefix;
      krem   = sh_k;
      __syncthreads();
    }
    vstar = prefix;
    meq   = krem;
  }

  float4 tq[4];
#pragma unroll
  for (int q = 0; q < 4; ++q)
    tq[q] = reinterpret_cast<const float4*>(tcol)[tid * 4 + q];
  int cnt = 0;
#pragma unroll
  for (int q = 0; q < 4; ++q) {
    cnt += (__float_as_uint(tq[q].x) == vstar);
    cnt += (__float_as_uint(tq[q].y) == vstar);
    cnt += (__float_as_uint(tq[q].z) == vstar);
    cnt += (__float_as_uint(tq[q].w) == vstar);
  }
  int inc = cnt;
#pragma unroll
  for (int off = 1; off < 64; off <<= 1) {
    int t = __shfl_up(inc, off);
    if (lane >= off) inc += t;
  }
  if (lane == 63) wcnt[wid] = inc;
  __syncthreads();
  if (tid == 0) {
    int run = 0;
    for (int w = 0; w < 16; ++w) { int t = wcnt[w]; wcnt[w] = run; run += t; }
  }
  __syncthreads();
  int exc = (inc - cnt) + wcnt[wid];

  float* ccol = combT + (size_t)e * N_TOK;
#pragma unroll
  for (int q = 0; q < 4; ++q) {
    float4 gq = reinterpret_cast<const float4*>(gcol)[tid * 4 + q];
    float ov[4];
    const float tv[4] = {tq[q].x, tq[q].y, tq[q].z, tq[q].w};
    const float gv[4] = {gq.x, gq.y, gq.z, gq.w};
#pragma unroll
    for (int j = 0; j < 4; ++j) {
      unsigned u = __float_as_uint(tv[j]);
      bool keep;
      if (u == vstar) { keep = (exc < meq); ++exc; }
      else            { keep = (u > vstar); }
      ov[j] = (keep && u != 0u) ? gv[j] : 0.f;
    }
    reinterpret_cast<float4*>(ccol)[tid * 4 + q] =
        make_float4(ov[0], ov[1], ov[2], ov[3]);
  }
}

// ---------------------------------------------------------------------------
// Kernel 4: transpose combT[e][t] -> out[t][e]; block 0 also computes l_aux
// ---------------------------------------------------------------------------
__global__ __launch_bounds__(1024) void transpose_out(
    const float* __restrict__ combT, float* __restrict__ out1,
    const float* __restrict__ me_sum, const int* __restrict__ ce_cnt,
    float* __restrict__ out0) {
  __shared__ float tile[64][65];
  const int tid  = (int)threadIdx.x;
  const int lane = tid & 63;
  const int wid  = tid >> 6;
  const int tok0 = (int)blockIdx.x * 64;
#pragma unroll
  for (int p = 0; p < 4; ++p) {
    const int e = p * 16 + wid;
    tile[lane][e] = combT[(size_t)e * N_TOK + tok0 + lane];
  }
  __syncthreads();
#pragma unroll
  for (int q = 0; q < 4; ++q) {
    const int tok = q * 16 + wid;
    out1[(size_t)(tok0 + tok) * NEXP + lane] = tile[tok][lane];
  }
  if (blockIdx.x == 0 && wid == 0) {
    float v = (me_sum[lane] / (float)N_TOK) *
              ((float)ce_cnt[lane] / (float)N_TOK);
#pragma unroll
    for (int off = 32; off > 0; off >>= 1) v += __shfl_xor(v, off);
    if (lane == 0) out0[0] = v * (float)NEXP;
  }
}

// ---------------------------------------------------------------------------
extern "C" void kernel_launch(void* const* d_in, const int* in_sizes, int n_in,
                              void* d_out, int out_size, void* d_ws, size_t ws_size,
                              hipStream_t stream) {
  const float* x = (const float*)d_in[0];
  const float* W = (const float*)d_in[1];
  float* out = (float*)d_out;
  float* ws  = (float*)d_ws;

  // KS=8 needs (8+2)*4MB scratch; fall back to KS=4 if ws is smaller.
  const bool ks8 = ws_size >= (size_t)(8 + 2) * NE_TOT * 4 + 1024;

  const int KS = ks8 ? 8 : 4;
  float* part   = ws;                       // KS * 4 MB
  float* combT  = ws;                       // aliases part (dead by then)
  float* gatesT = ws + (size_t)KS * NE_TOT; // 4 MB
  float* tamT   = gatesT + NE_TOT;          // 4 MB
  float* me     = tamT + NE_TOT;
  int*   ce     = (int*)(me + 64);

  // W digit arrays (768 KB) live in the gatesT region: written by wdigits,
  // consumed by gemm_mfma, dead before gate_rows overwrites gatesT.
  unsigned short* Wh = (unsigned short*)gatesT;
  unsigned short* Wl = Wh + (size_t)NEXP * KDIM;
  unsigned short* Wq = Wl + (size_t)NEXP * KDIM;

  wdigits<<<(NEXP * KDIM) / 256, 256, 0, stream>>>(W, Wh, Wl, Wq);
  if (ks8) gemm_mfma<8><<<64 * 8, 256, 0, stream>>>(x, Wh, Wl, Wq, part);
  else     gemm_mfma<4><<<64 * 4, 256, 0, stream>>>(x, Wh, Wl, Wq, part);
  if (ks8) gate_rows<8><<<N_TOK / 64, 1024, 0, stream>>>(part, gatesT, tamT);
  else     gate_rows<4><<<N_TOK / 64, 1024, 0, stream>>>(part, gatesT, tamT);
  expert_select<<<NEXP, 1024, 0, stream>>>(gatesT, tamT, me, ce, combT);
  transpose_out<<<N_TOK / 64, 1024, 0, stream>>>(combT, out + 1, me, ce, out);
}